// Round 7
// baseline (81.532 us; speedup 1.0000x reference)
//
#include <hip/hip_runtime.h>
#include <math.h>

typedef short bf16x8 __attribute__((ext_vector_type(8)));
typedef float f32x4 __attribute__((ext_vector_type(4)));
typedef unsigned int uint32;

#define BETA 10.0f
#define THRESH -80.0f
// Certificate: bound = max_ct(20*max_allrows(acc) + c2_ct) + max_rows(-10*||x||^2)
// >= true max arg. A,B RTNE bf16 -> 20*|dot err| <= ~4; bf16 x2 adds <= ~3.
// Not fired => true arg <= -73 => contribution <= exp(-73)*1024*0.02 ~ 4e-30
// << 1.5e-2. If fired, cold path recomputes exact fp32 from x/centers.

// LDS map (GLDS region [C_OFF..C2_OFF+4K) linear & contiguous)
#define C_OFF    0         // 131072 B: centers bf16, chunk layout
#define C2_OFF   131072    // 4096 B: -BETA*||c_j||^2 fp32
#define XB_OFF   135168    // 16384 B: x bf16 chunk layout (one 128-row tile)
#define W_OFF    151552    // 768 B: W_x fp32 [3][64]
#define X2_OFF   152320    // 2 x 512 B: ||x_r||^2 per tile
#define RED_OFF  153344    // 2 x 1536 B: out accumulators [tile][128][3]
#define LDS_TOT  156416    // 152.75 KB -> 1 block/CU, 16 waves = 4/SIMD

__device__ __forceinline__ uint32 f2bf_rtne(float f) {
    uint32 u = __float_as_uint(f);
    u += 0x7FFFu + ((u >> 16) & 1u);
    return u >> 16;
}
__device__ __forceinline__ uint32 pk_rtne(float a, float b) {
    return f2bf_rtne(a) | (f2bf_rtne(b) << 16);
}
__device__ __forceinline__ float bf2f(short s) {
    return __uint_as_float(((uint32)(unsigned short)s) << 16);
}
__device__ __forceinline__ f32x4 vmax4(f32x4 a, f32x4 b) {
    f32x4 r;
    r[0] = fmaxf(a[0], b[0]); r[1] = fmaxf(a[1], b[1]);
    r[2] = fmaxf(a[2], b[2]); r[3] = fmaxf(a[3], b[3]);
    return r;
}

#define GLDS(g, l) __builtin_amdgcn_global_load_lds( \
    (const __attribute__((address_space(1))) unsigned int*)(g), \
    (__attribute__((address_space(3))) unsigned int*)(l), 16, 0, 0)

// Prep: centers -> bf16 RTNE chunk layout + c2m[j] = -BETA*||c_j||^2.
__global__ void rbfn_prep(const float* __restrict__ centers,
                          uint32* __restrict__ cbf,
                          float* __restrict__ c2m) {
    const int tid = threadIdx.x;
    const int j = blockIdx.x * 64 + (tid >> 2);
    const int seg = tid & 3;
    const float4* cp = (const float4*)(centers + j * 64 + seg * 16);
    const float4 f0 = cp[0], f1 = cp[1], f2 = cp[2], f3 = cp[3];
    float s = f0.x*f0.x + f0.y*f0.y + f0.z*f0.z + f0.w*f0.w
            + f1.x*f1.x + f1.y*f1.y + f1.z*f1.z + f1.w*f1.w
            + f2.x*f2.x + f2.y*f2.y + f2.z*f2.z + f2.w*f2.w
            + f3.x*f3.x + f3.y*f3.y + f3.z*f3.z + f3.w*f3.w;
    uint4 p0, p1;
    p0.x = pk_rtne(f0.x, f0.y); p0.y = pk_rtne(f0.z, f0.w);
    p0.z = pk_rtne(f1.x, f1.y); p0.w = pk_rtne(f1.z, f1.w);
    p1.x = pk_rtne(f2.x, f2.y); p1.y = pk_rtne(f2.z, f2.w);
    p1.z = pk_rtne(f3.x, f3.y); p1.w = pk_rtne(f3.z, f3.w);
    char* base = (char*)cbf + (j >> 4) * 2048 + (j & 15) * 16;
    *(uint4*)(base + (seg * 2 + 0) * 256) = p0;
    *(uint4*)(base + (seg * 2 + 1) * 256) = p1;
    s += __shfl_xor(s, 1);
    s += __shfl_xor(s, 2);
    if (seg == 0) c2m[j] = -BETA * s;
}

// Main: persistent block = 256 rows (2 tiles of 128) x 1024 centers.
// Grid 256 = 1 block/CU; 1024 thr = 16 waves = 4 waves/SIMD (latency hiding).
// Wave = rowgrp (2 x 64 rows) x colgrp (8 x 128 cols).
__global__ __launch_bounds__(1024) void rbfn_main(
    const float* __restrict__ x,
    const char* __restrict__ ws,      // [cbf 128K][c2m 4K] linear
    const float* __restrict__ W,
    const float* __restrict__ bias,
    const float* __restrict__ centers,
    float* __restrict__ out)
{
    __shared__ __align__(16) char lds[LDS_TOT];

    const int tid = threadIdx.x;
    const int wv = tid >> 6;
    const int lane = tid & 63;
    const int quad = lane >> 4;
    const int l15 = lane & 15;
    const int rowgrp = wv & 1;    // 64-row half of the 128-row tile
    const int colgrp = wv >> 1;   // 0..7 -> 128 cols
    const int row0 = blockIdx.x * 256;

    const float bb0 = bias[0], bb1 = bias[1], bb2 = bias[2];

    // ---- coalesced async stage: centers bf16 + c2 (132 KB linear), once ----
    {
        const char* g = ws + wv * 8192 + lane * 16;
        char* l = lds + wv * 8192;
        #pragma unroll
        for (int it = 0; it < 8; ++it)
            GLDS(g + it * 1024, l + it * 1024);
        if (wv < 4)
            GLDS(ws + 131072 + wv * 1024 + lane * 16, lds + C2_OFF + wv * 1024);
    }

    // ---- both x tiles -> registers up-front (fully coalesced) ----
    float4 xv[2][2];
    {
        const float4* xg = (const float4*)(x + (size_t)row0 * 64);
        #pragma unroll
        for (int t = 0; t < 2; ++t)
            #pragma unroll
            for (int i = 0; i < 2; ++i)
                xv[t][i] = xg[t * 2048 + i * 1024 + tid];
    }
    // ---- W_x (3x64 fp32) -> LDS ----
    if (tid < 48) {
        const int k = tid >> 4, c = tid & 15;
        *((float4*)(lds + W_OFF) + tid) = *((const float4*)(W + k * 1088) + c);
    }
    // ---- x tile 0 -> LDS chunk layout ----
    #pragma unroll
    for (int i = 0; i < 2; ++i) {
        const int f = i * 1024 + tid;           // float4 index in tile
        const float4 v = xv[0][i];
        const int row = f >> 4, sg = f & 15;
        uint2 q; q.x = pk_rtne(v.x, v.y); q.y = pk_rtne(v.z, v.w);
        *(uint2*)(lds + XB_OFF + (row >> 4) * 2048 + (sg >> 1) * 256 +
                  (row & 15) * 16 + (sg & 1) * 8) = q;
    }

    __syncthreads();   // GLDS + x0 + W staged

    // ---- per-lane column constants (tile-invariant) ----
    float c2r[8];
    {
        const float* c2p = (const float*)(lds + C2_OFF) + colgrp * 128 + l15;
        #pragma unroll
        for (int ct = 0; ct < 8; ++ct) c2r[ct] = c2p[ct * 16];
    }
    const char* cB = lds + C_OFF + colgrp * 16384 + quad * 256 + l15 * 16;

    #pragma unroll
    for (int t = 0; t < 2; ++t) {
        // ---- A fragments from LDS (contiguous stripes) ----
        bf16x8 af[4][2];
        #pragma unroll
        for (int rt = 0; rt < 4; ++rt) {
            const char* ab = lds + XB_OFF + (rowgrp * 4 + rt) * 2048 + l15 * 16;
            af[rt][0] = *(const bf16x8*)(ab + quad * 256);
            af[rt][1] = *(const bf16x8*)(ab + (4 + quad) * 256);
        }
        // ---- x2 + Wx dots: thread = (row r, eighth e) ----
        {
            const int r = tid >> 3, e = tid & 7;
            const bf16x8 h = *(const bf16x8*)(lds + XB_OFF + (r >> 4) * 2048 +
                                              e * 256 + (r & 15) * 16);
            const float* w0 = (const float*)(lds + W_OFF) + 0 * 64 + e * 8;
            const float* w1 = (const float*)(lds + W_OFF) + 1 * 64 + e * 8;
            const float* w2 = (const float*)(lds + W_OFF) + 2 * 64 + e * 8;
            float s2 = 0.f, d0 = 0.f, d1 = 0.f, d2 = 0.f;
            #pragma unroll
            for (int i = 0; i < 8; ++i) {
                const float a = bf2f(h[i]);
                s2 = fmaf(a, a, s2);
                d0 = fmaf(a, w0[i], d0);
                d1 = fmaf(a, w1[i], d1);
                d2 = fmaf(a, w2[i], d2);
            }
            #pragma unroll
            for (int m = 1; m <= 4; m <<= 1) {
                s2 += __shfl_xor(s2, m);
                d0 += __shfl_xor(d0, m);
                d1 += __shfl_xor(d1, m);
                d2 += __shfl_xor(d2, m);
            }
            if (e == 0) {
                ((float*)(lds + X2_OFF + t * 512))[r] = s2;
                float* red = (float*)(lds + RED_OFF + t * 1536);
                red[r * 3 + 0] = d0 + bb0;
                red[r * 3 + 1] = d1 + bb1;
                red[r * 3 + 2] = d2 + bb2;
            }
        }
        __syncthreads();   // XB(t) readers done; x2/red(t) seeded

        // ---- stage next tile's x into XB (dead for tile t now) ----
        if (t == 0) {
            #pragma unroll
            for (int i = 0; i < 2; ++i) {
                const int f = i * 1024 + tid;
                const float4 v = xv[1][i];
                const int row = f >> 4, sg = f & 15;
                uint2 q; q.x = pk_rtne(v.x, v.y); q.y = pk_rtne(v.z, v.w);
                *(uint2*)(lds + XB_OFF + (row >> 4) * 2048 + (sg >> 1) * 256 +
                          (row & 15) * 16 + (sg & 1) * 8) = q;
            }
        }

        // ---- prermax = -BETA * min over this lane's 16 output rows ----
        const float* px2 = (const float*)(lds + X2_OFF + t * 512) + rowgrp * 64;
        float mn = 1e30f;
        #pragma unroll
        for (int rt = 0; rt < 4; ++rt) {
            const float4 q4 = *(const float4*)(px2 + rt * 16 + quad * 4);
            mn = fminf(mn, fminf(fminf(q4.x, q4.y), fminf(q4.z, q4.w)));
        }
        const float prermax = -BETA * mn;

        // ---- hot loop: 8 col-tiles, branch-free, 8 MFMA per ct ----
        float gm = -1e30f;
        #pragma unroll
        for (int ct = 0; ct < 8; ++ct) {
            const bf16x8 b0 = *(const bf16x8*)(cB + ct * 2048);
            const bf16x8 b1 = *(const bf16x8*)(cB + ct * 2048 + 1024);
            f32x4 acc[4];
            #pragma unroll
            for (int rt = 0; rt < 4; ++rt) {
                const f32x4 z = {0.f, 0.f, 0.f, 0.f};
                acc[rt] = __builtin_amdgcn_mfma_f32_16x16x32_bf16(af[rt][0], b0, z, 0, 0, 0);
                acc[rt] = __builtin_amdgcn_mfma_f32_16x16x32_bf16(af[rt][1], b1, acc[rt], 0, 0, 0);
            }
            f32x4 m0 = vmax4(vmax4(acc[0], acc[1]), vmax4(acc[2], acc[3]));
            const float m = fmaxf(fmaxf(m0[0], m0[1]), fmaxf(m0[2], m0[3]));
            gm = fmaxf(gm, fmaf(2.0f * BETA, m, c2r[ct]));
        }
        const float bound = gm + prermax;

        // ---- cold exact path (statistically never) ----
        if (__builtin_expect(__ballot(bound > THRESH) != 0ull, 0)) {
            float* red = (float*)(lds + RED_OFF + t * 1536);
            #pragma clang loop unroll(disable)
            for (int ct = 0; ct < 8; ++ct) {
                const int j = colgrp * 128 + ct * 16 + l15;
                #pragma clang loop unroll(disable)
                for (int rr = 0; rr < 16; ++rr) {
                    const int r = rowgrp * 64 + (rr >> 2) * 16 + quad * 4 + (rr & 3);
                    const float* xr = x + (size_t)(row0 + t * 128 + r) * 64;
                    const float* cr = centers + (size_t)j * 64;
                    float d2 = 0.f;
                    #pragma clang loop unroll(disable)
                    for (int k = 0; k < 64; ++k) {
                        const float df = xr[k] - cr[k];
                        d2 = fmaf(df, df, d2);
                    }
                    const float arg = -BETA * d2;
                    if (arg > -87.f) {
                        const float e = expf(arg);
                        atomicAdd(&red[r * 3 + 0], e * W[0 * 1088 + 64 + j]);
                        atomicAdd(&red[r * 3 + 1], e * W[1 * 1088 + 64 + j]);
                        atomicAdd(&red[r * 3 + 2], e * W[2 * 1088 + 64 + j]);
                    }
                }
            }
        }
        __syncthreads();   // red(t) final; XB holds tile t+1

        // ---- coalesced store for this tile ----
        if (tid < 96)
            ((float4*)out)[blockIdx.x * 192 + t * 96 + tid] =
                *((const float4*)(lds + RED_OFF + t * 1536) + tid);
    }
}

extern "C" void kernel_launch(void* const* d_in, const int* in_sizes, int n_in,
                              void* d_out, int out_size, void* d_ws, size_t ws_size,
                              hipStream_t stream) {
    const float* x       = (const float*)d_in[0];
    const float* centers = (const float*)d_in[1];
    const float* W       = (const float*)d_in[2];
    const float* b       = (const float*)d_in[3];
    float* out = (float*)d_out;

    uint32* cbf = (uint32*)d_ws;                        // 128 KB bf16 chunks
    float*  c2m = (float*)((char*)d_ws + 131072);       // 4 KB -B*||c||^2

    const int n = in_sizes[0] / 64;                     // 65536 rows

    rbfn_prep<<<16, 256, 0, stream>>>(centers, cbf, c2m);
    rbfn_main<<<n / 256, 1024, 0, stream>>>(x, (const char*)d_ws, W, b, centers, out);
}

// Round 8
// 81.510 us; speedup vs baseline: 1.0003x; 1.0003x over previous
//
#include <hip/hip_runtime.h>
#include <math.h>

typedef short bf16x8 __attribute__((ext_vector_type(8)));
typedef float f32x4 __attribute__((ext_vector_type(4)));
typedef unsigned int uint32;

#define BETA 10.0f
#define THRESH -80.0f
// Certificate: bound = max_ct(20*max_rows(acc) + c2_ct) + max_rows(-10*||x||^2)
// >= true max arg. A,B RTNE bf16 -> 20*|dot err| <= ~4; bf16-squared x2/c2
// add <= ~10 total. Not fired => true arg <= -66 => contribution
// <= exp(-66)*1024*0.02 ~ 5e-27 << 1.5e-2. If fired, cold path is exact fp32.

// LDS map
#define C_OFF   0          // 131072 B: centers bf16, chunk layout
#define XB_OFF  131072     // 16384 B: x bf16, chunk layout (one 128-row tile)
#define RED_OFF 147456     // 2 x 1536 B: out accumulators [tile][128][3]
#define LDS_TOT 150528     // 147 KB -> 1 block/CU

__device__ __forceinline__ uint32 f2bf_rtne(float f) {
    uint32 u = __float_as_uint(f);
    u += 0x7FFFu + ((u >> 16) & 1u);
    return u >> 16;
}
__device__ __forceinline__ uint32 pk_rtne(float a, float b) {
    return f2bf_rtne(a) | (f2bf_rtne(b) << 16);
}
__device__ __forceinline__ f32x4 vmax4(f32x4 a, f32x4 b) {
    f32x4 r;
    r[0] = fmaxf(a[0], b[0]); r[1] = fmaxf(a[1], b[1]);
    r[2] = fmaxf(a[2], b[2]); r[3] = fmaxf(a[3], b[3]);
    return r;
}
#define MFMA __builtin_amdgcn_mfma_f32_16x16x32_bf16

// Single fused kernel. Persistent block = 256 rows (2 tiles of 128) x 1024
// centers. Grid 256 = 1 block/CU; 512 thr = 8 waves (2/SIMD, LDS-traffic
// optimal). Wave = all 128 rows x 128-col group. Chunk layout (16-B chunk
// c = k/8 of vector j at (j>>4)*2048 + c*256 + (j&15)*16) is simultaneously
// a valid MFMA A-frag and B-frag source, so norms come from mfma(v,v) diags.
__global__ __launch_bounds__(512) void rbfn_fused(
    const float* __restrict__ x,
    const float* __restrict__ centers,
    const float* __restrict__ W,
    const float* __restrict__ bias,
    float* __restrict__ out)
{
    __shared__ __align__(16) char lds[LDS_TOT];

    const int tid = threadIdx.x;
    const int wv = tid >> 6;
    const int lane = tid & 63;
    const int quad = lane >> 4;
    const int l15 = lane & 15;
    const int row0 = blockIdx.x * 256;

    // ---- x for both tiles -> registers (fully coalesced, HBM in flight) ----
    float4 x0[4], x1[4];
    {
        const float4* xg = (const float4*)(x + (size_t)row0 * 64);
        #pragma unroll
        for (int i = 0; i < 4; ++i) x0[i] = xg[i * 512 + tid];
        #pragma unroll
        for (int i = 0; i < 4; ++i) x1[i] = xg[2048 + i * 512 + tid];
    }

    // ---- centers fp32 -> bf16 chunk layout in LDS (coalesced, L2) ----
    {
        const float4* cf4 = (const float4*)centers;
        #pragma unroll 8
        for (int i = 0; i < 32; ++i) {
            const int f = i * 512 + tid;
            const float4 v = cf4[f];
            const int j = f >> 4, sg = f & 15;
            uint2 q; q.x = pk_rtne(v.x, v.y); q.y = pk_rtne(v.z, v.w);
            *(uint2*)(lds + C_OFF + (j >> 4) * 2048 + (sg >> 1) * 256 +
                      (j & 15) * 16 + (sg & 1) * 8) = q;
        }
    }
    // ---- x tile 0 -> LDS chunk layout ----
    #pragma unroll
    for (int i = 0; i < 4; ++i) {
        const int f = i * 512 + tid;
        const float4 v = x0[i];
        const int r = f >> 4, sg = f & 15;
        uint2 q; q.x = pk_rtne(v.x, v.y); q.y = pk_rtne(v.z, v.w);
        *(uint2*)(lds + XB_OFF + (r >> 4) * 2048 + (sg >> 1) * 256 +
                  (r & 15) * 16 + (sg & 1) * 8) = q;
    }

    // ---- wave 0: Wx B-fragments, hi/lo bf16 split (exactness) ----
    bf16x8 bwh[2], bwl[2];
    float bl = 0.f;
    if (wv == 0) {
        if (l15 < 3) bl = bias[l15];
        #pragma unroll
        for (int kk = 0; kk < 2; ++kk) {
            bf16x8 h, l;
            #pragma unroll
            for (int e = 0; e < 8; ++e) {
                const float w = (l15 < 3) ? W[l15 * 1088 + kk * 32 + quad * 8 + e] : 0.f;
                const uint32 hb = f2bf_rtne(w);
                h[e] = (short)hb;
                l[e] = (short)f2bf_rtne(w - __uint_as_float(hb << 16));
            }
            bwh[kk] = h; bwl[kk] = l;
        }
    }

    __syncthreads();   // C + XB(0) staged

    const char* cB = lds + C_OFF + wv * 16384 + quad * 256 + l15 * 16;
    float c2r[8];

    #pragma unroll
    for (int t = 0; t < 2; ++t) {
        // ---- A fragments (contiguous b128, bank-floor) ----
        bf16x8 af[8][2];
        #pragma unroll
        for (int rt = 0; rt < 8; ++rt) {
            const char* ab = lds + XB_OFF + rt * 2048 + l15 * 16;
            af[rt][0] = *(const bf16x8*)(ab + quad * 256);
            af[rt][1] = *(const bf16x8*)(ab + (4 + quad) * 256);
        }

        // ---- ||x||^2 via mfma(af, af) diagonal; wave-local shfl extract ----
        float mn = 1e30f;
        #pragma unroll
        for (int rt = 0; rt < 8; ++rt) {
            const f32x4 z = {0.f, 0.f, 0.f, 0.f};
            f32x4 d = MFMA(af[rt][0], af[rt][0], z, 0, 0, 0);
            d = MFMA(af[rt][1], af[rt][1], d, 0, 0, 0);
            #pragma unroll
            for (int reg = 0; reg < 4; ++reg)
                mn = fminf(mn, __shfl(d[reg], quad * 20 + reg));
        }
        const float prermax = -BETA * mn;

        // ---- t==0: ||c||^2 for this wave's 128 cols, same trick ----
        if (t == 0) {
            #pragma unroll
            for (int ct = 0; ct < 8; ++ct) {
                const bf16x8 b0 = *(const bf16x8*)(cB + ct * 2048);
                const bf16x8 b1 = *(const bf16x8*)(cB + ct * 2048 + 1024);
                const f32x4 z = {0.f, 0.f, 0.f, 0.f};
                f32x4 d = MFMA(b0, b0, z, 0, 0, 0);
                d = MFMA(b1, b1, d, 0, 0, 0);
                const float dv = (l15 & 2) ? ((l15 & 1) ? d[3] : d[2])
                                           : ((l15 & 1) ? d[1] : d[0]);
                c2r[ct] = -BETA * __shfl(dv, (l15 >> 2) * 16 + l15);
            }
        }

        // ---- wave 0: exact-ish x@Wx^T via MFMA (hi+lo), seed red[t] ----
        if (wv == 0) {
            float* redf = (float*)(lds + RED_OFF + t * 1536);
            #pragma unroll
            for (int rt = 0; rt < 8; ++rt) {
                const f32x4 z = {0.f, 0.f, 0.f, 0.f};
                f32x4 aw = MFMA(af[rt][0], bwh[0], z, 0, 0, 0);
                aw = MFMA(af[rt][1], bwh[1], aw, 0, 0, 0);
                aw = MFMA(af[rt][0], bwl[0], aw, 0, 0, 0);
                aw = MFMA(af[rt][1], bwl[1], aw, 0, 0, 0);
                if (l15 < 3) {
                    #pragma unroll
                    for (int reg = 0; reg < 4; ++reg)
                        redf[(rt * 16 + quad * 4 + reg) * 3 + l15] = aw[reg] + bl;
                }
            }
        }

        __syncthreads();   // af reads + red seeds done

        // ---- stage next tile's x (XB now dead for tile t) ----
        if (t == 0) {
            #pragma unroll
            for (int i = 0; i < 4; ++i) {
                const int f = i * 512 + tid;
                const float4 v = x1[i];
                const int r = f >> 4, sg = f & 15;
                uint2 q; q.x = pk_rtne(v.x, v.y); q.y = pk_rtne(v.z, v.w);
                *(uint2*)(lds + XB_OFF + (r >> 4) * 2048 + (sg >> 1) * 256 +
                          (r & 15) * 16 + (sg & 1) * 8) = q;
            }
        }

        // ---- hot loop: 8 col-tiles, branch-free, 16 MFMA per B-pair ----
        float gm = -1e30f;
        #pragma unroll
        for (int ct = 0; ct < 8; ++ct) {
            const bf16x8 b0 = *(const bf16x8*)(cB + ct * 2048);
            const bf16x8 b1 = *(const bf16x8*)(cB + ct * 2048 + 1024);
            f32x4 acc[8];
            #pragma unroll
            for (int rt = 0; rt < 8; ++rt) {
                const f32x4 z = {0.f, 0.f, 0.f, 0.f};
                acc[rt] = MFMA(af[rt][0], b0, z, 0, 0, 0);
                acc[rt] = MFMA(af[rt][1], b1, acc[rt], 0, 0, 0);
            }
            f32x4 m0 = vmax4(vmax4(acc[0], acc[1]), vmax4(acc[2], acc[3]));
            f32x4 m1 = vmax4(vmax4(acc[4], acc[5]), vmax4(acc[6], acc[7]));
            m0 = vmax4(m0, m1);
            const float m = fmaxf(fmaxf(m0[0], m0[1]), fmaxf(m0[2], m0[3]));
            gm = fmaxf(gm, fmaf(2.0f * BETA, m, c2r[ct]));
        }
        const float bound = gm + prermax;

        // ---- cold exact path (statistically never; unconditional safety) ----
        if (__builtin_expect(__ballot(bound > THRESH) != 0ull, 0)) {
            float* red = (float*)(lds + RED_OFF + t * 1536);
            #pragma clang loop unroll(disable)
            for (int ct = 0; ct < 8; ++ct) {
                const int j = wv * 128 + ct * 16 + l15;
                #pragma clang loop unroll(disable)
                for (int rr = 0; rr < 32; ++rr) {
                    const int r = (rr >> 2) * 16 + quad * 4 + (rr & 3);
                    const float* xr = x + (size_t)(row0 + t * 128 + r) * 64;
                    const float* cr = centers + (size_t)j * 64;
                    float d2 = 0.f;
                    #pragma clang loop unroll(disable)
                    for (int k = 0; k < 64; ++k) {
                        const float df = xr[k] - cr[k];
                        d2 = fmaf(df, df, d2);
                    }
                    const float arg = -BETA * d2;
                    if (arg > -87.f) {
                        const float e = expf(arg);
                        atomicAdd(&red[r * 3 + 0], e * W[0 * 1088 + 64 + j]);
                        atomicAdd(&red[r * 3 + 1], e * W[1 * 1088 + 64 + j]);
                        atomicAdd(&red[r * 3 + 2], e * W[2 * 1088 + 64 + j]);
                    }
                }
            }
        }
        __syncthreads();   // red(t) final; XB holds tile t+1

        // ---- coalesced store for this tile ----
        if (tid < 96)
            ((float4*)out)[blockIdx.x * 192 + t * 96 + tid] =
                *((const float4*)(lds + RED_OFF + t * 1536) + tid);
    }
}

extern "C" void kernel_launch(void* const* d_in, const int* in_sizes, int n_in,
                              void* d_out, int out_size, void* d_ws, size_t ws_size,
                              hipStream_t stream) {
    const float* x       = (const float*)d_in[0];
    const float* centers = (const float*)d_in[1];
    const float* W       = (const float*)d_in[2];
    const float* b       = (const float*)d_in[3];
    float* out = (float*)d_out;

    const int n = in_sizes[0] / 64;   // 65536 rows
    rbfn_fused<<<n / 256, 512, 0, stream>>>(x, centers, W, b, out);
}